// Round 5
// baseline (562.352 us; speedup 1.0000x reference)
//
#include <hip/hip_runtime.h>
#include <hip/hip_bf16.h>
#include <cstdint>

// Problem constants: x is (4096, 3, 4096) fp32; q/k/v are (4096, 4096).
#define N 4096
#define ROWSTRIDE 12288  // 3*4096 floats per n-index

typedef __attribute__((ext_vector_type(8))) _Float16 half8;
typedef __attribute__((ext_vector_type(4))) _Float16 half4v;
typedef __attribute__((ext_vector_type(4))) float floatx4;

// ---------------------------------------------------------------------------
// Pack q,k (fp32 strided rows) -> fp16 dense row-major. q is pre-scaled by 0.5
// 32B loads / 16B stores per thread.
// ---------------------------------------------------------------------------
__global__ __launch_bounds__(256) void pack_qk(const float* __restrict__ x,
                                               _Float16* __restrict__ qh,
                                               _Float16* __restrict__ kh) {
    const size_t tid = (size_t)blockIdx.x * 256 + threadIdx.x;  // 4096*512 threads
    const int i  = (int)(tid >> 9);   // row 0..4095
    const int c8 = (int)(tid & 511);  // 8-float chunk within 4096-wide row
    const float4* xr = (const float4*)(x + (size_t)i * ROWSTRIDE);
    float4 qa = xr[c8 * 2], qb = xr[c8 * 2 + 1];
    float4 ka = xr[1024 + c8 * 2], kb = xr[1024 + c8 * 2 + 1];
    half8 qo = {(_Float16)(qa.x * 0.5f), (_Float16)(qa.y * 0.5f),
                (_Float16)(qa.z * 0.5f), (_Float16)(qa.w * 0.5f),
                (_Float16)(qb.x * 0.5f), (_Float16)(qb.y * 0.5f),
                (_Float16)(qb.z * 0.5f), (_Float16)(qb.w * 0.5f)};
    half8 ko = {(_Float16)ka.x, (_Float16)ka.y, (_Float16)ka.z, (_Float16)ka.w,
                (_Float16)kb.x, (_Float16)kb.y, (_Float16)kb.z, (_Float16)kb.w};
    *(half8*)(qh + (size_t)i * N + c8 * 8) = qo;
    *(half8*)(kh + (size_t)i * N + c8 * 8) = ko;
}

// ---------------------------------------------------------------------------
// v (fp32, strided rows) -> vt fp16 with vt[d][j] = v[j][d]
// 64(j) x 64(d) tile; stores are 8 lanes x 16B = 128B contiguous segments.
// ---------------------------------------------------------------------------
__global__ __launch_bounds__(256) void transpose_v(const float* __restrict__ x,
                                                   _Float16* __restrict__ vt) {
    __shared__ float tile[64][65];  // +1 pad: store-phase reads ~2-way (free)
    const int j0 = blockIdx.x * 64;  // v row block
    const int d0 = blockIdx.y * 64;  // v col block
    const int t  = threadIdx.x;
#pragma unroll
    for (int it = 0; it < 4; ++it) {
        const int r  = it * 16 + (t >> 4);  // 0..63
        const int c4 = t & 15;              // float4 within 64 cols
        const float4 val =
            *(const float4*)(x + (size_t)(j0 + r) * ROWSTRIDE + 8192 + d0 + c4 * 4);
        tile[r][c4 * 4 + 0] = val.x;
        tile[r][c4 * 4 + 1] = val.y;
        tile[r][c4 * 4 + 2] = val.z;
        tile[r][c4 * 4 + 3] = val.w;
    }
    __syncthreads();
#pragma unroll
    for (int it = 0; it < 2; ++it) {
        const int dr = it * 32 + (t >> 3);  // 0..63: d row
        const int jc = t & 7;               // 8-wide j chunk
        half8 o;
#pragma unroll
        for (int jj = 0; jj < 8; ++jj) o[jj] = (_Float16)tile[jc * 8 + jj][dr];
        *(half8*)(vt + (size_t)(d0 + dr) * N + j0 + jc * 8) = o;
    }
}

// ---------------------------------------------------------------------------
// NT GEMM, fp16 in / fp32 out, M=N=K=4096: C[i][j] = sum_k A[i][k]*Bt[j][k]
//
// 256x256-tile, single-barrier-per-phase, DEEP-PREFETCH schedule:
//  - 512 threads = 8 waves (2M x 4N); per-wave C = 128x64 (8x4 frags).
//  - LDS 128 KiB = 8 regions [buf][khalf][A|B] of 256 rows x 32 k fp16.
//  - 4 phases per K-tile. ALL 8 stage-loads for kt+1 issue in phases 0-1 of
//    kt (4 at ph0: A'kh0+B'kh0; 4 at ph1: A'kh1+B'kh1). Gates: vmcnt(8)@ph1
//    (retires rb-kh1, read ph2/ph3: 4-phase shadow), vmcnt(4)@ph3 (retires
//    sb-kh0, read kt+1 ph0/ph1: 3-phase shadow). Never vmcnt(0) mid-loop.
//  - WAR safety: per region, all waves' lgkmcnt(0) drain of last reads
//    precedes >=1 full s_barrier before any wave issues the overwrite
//    (kh0-A: 2 barriers, kh0-B: 3, kh1-A: 1, kh1-B: 2).
//  - T2 swizzle: 16B-chunk c' = c ^ ((row>>1)&3) on ds_read addr, inverse
//    pre-applied on global source addr; LDS dest linear. 0 conflicts meas.
//  - T1: XCD-bijective block swizzle (256 blocks = 8 XCDs x 32).
// ---------------------------------------------------------------------------
#define GL2LDS(g, l)                                                                     \
    __builtin_amdgcn_global_load_lds((const __attribute__((address_space(1))) void*)(g), \
                                     (__attribute__((address_space(3))) void*)(l), 16, 0, 0)

__global__ __launch_bounds__(512, 2) void gemm_nt256(const _Float16* __restrict__ A,
                                                     const _Float16* __restrict__ Bt,
                                                     float* __restrict__ C) {
    __shared__ _Float16 lds[65536];  // 128 KiB
    const int t    = threadIdx.x;
    const int wave = t >> 6;
    const int lane = t & 63;
    const int wr   = wave >> 2;  // 0..1: M half
    const int wc   = wave & 3;   // 0..3: N quarter

    // XCD-aware bijective swizzle: 256 workgroups, 8 XCDs, 32 contiguous each.
    const int orig = blockIdx.y * 16 + blockIdx.x;
    const int wg   = (orig & 7) * 32 + (orig >> 3);
    const int rowBase = (wg >> 4) * 256;
    const int colBase = (wg & 15) * 256;

    floatx4 acc[8][4] = {};

    // ---- staging addressing (pre-swizzled global source; linear LDS dest) ----
    const int sRow = t >> 2;
    const int sCg  = (t & 3) ^ ((t >> 3) & 3);  // chunk ^ (row>>1)&3
    const _Float16* gA = A  + (size_t)(rowBase + sRow) * N + sCg * 8;
    const _Float16* gB = Bt + (size_t)(colBase + sRow) * N + sCg * 8;
    const int ldsW = wave * 512;  // wave-uniform base within half-region (halves)

    // ---- fragment read addressing (swizzled chunk) ----
    const int fr   = lane & 15;
    const int quad = lane >> 4;
    const int swc  = quad ^ ((fr >> 1) & 3);
    const int rdA  = (wr * 128 + fr) * 32 + swc * 8;  // + mt*512 + region
    const int rdB  = (wc * 64 + fr) * 32 + swc * 8;   // + nt*512 + region

    // Region offsets (halves): [buf]*32768 + [khalf]*16384 + [B]*8192
#define STAGE(regOff, g, kOff)                                                  \
    do {                                                                        \
        GL2LDS((g) + (kOff), &lds[(regOff) + ldsW]);                            \
        GL2LDS((g) + (kOff) + (size_t)128 * N, &lds[(regOff) + 4096 + ldsW]);   \
    } while (0)

    // Prologue: stage kt=0 into buf0 (A-kh0, B-kh0, A-kh1, B-kh1).
    STAGE(0, gA, 0);
    STAGE(8192, gB, 0);
    STAGE(16384, gA, 32);
    STAGE(24576, gB, 32);
    asm volatile("s_waitcnt vmcnt(4)" ::: "memory");  // kh0 pair landed
    __builtin_amdgcn_s_barrier();

    for (int kt = 0; kt < 63; ++kt) {
        const int rb = (kt & 1) * 32768;  // read buffer
        const int sb = rb ^ 32768;        // stage buffer (kt+1)
        const int kNext = (kt + 1) * 64;
#pragma unroll
        for (int kh = 0; kh < 2; ++kh) {
            const int rA = rb + kh * 16384;
            const int rB = rA + 8192;
            half8 af[4], bf[4];
            // ---- phase lo: 8 frag reads; kh==0 also stages A'kh0+B'kh0 ----
#pragma unroll
            for (int nt = 0; nt < 4; ++nt) bf[nt] = *(const half8*)&lds[rB + nt * 512 + rdB];
#pragma unroll
            for (int mt = 0; mt < 4; ++mt) af[mt] = *(const half8*)&lds[rA + mt * 512 + rdA];
            if (kh == 0) {
                STAGE(sb, gA, kNext);
                STAGE(sb + 8192, gB, kNext);
            }
            __builtin_amdgcn_s_barrier();
            asm volatile("s_waitcnt lgkmcnt(0)" ::: "memory");
            __builtin_amdgcn_s_setprio(1);
#pragma unroll
            for (int mt = 0; mt < 4; ++mt)
#pragma unroll
                for (int nt = 0; nt < 4; ++nt)
                    acc[mt][nt] = __builtin_amdgcn_mfma_f32_16x16x32_f16(af[mt], bf[nt],
                                                                         acc[mt][nt], 0, 0, 0);
            __builtin_amdgcn_s_setprio(0);
            // ---- phase hi: 4 frag reads; kh==0 stages A'kh1+B'kh1 ----
#pragma unroll
            for (int mt = 0; mt < 4; ++mt) af[mt] = *(const half8*)&lds[rA + (mt + 4) * 512 + rdA];
            if (kh == 0) {
                STAGE(sb + 16384, gA, kNext + 32);
                STAGE(sb + 24576, gB, kNext + 32);
                // retire rb-kh1 pair (issued kt-1 ph1 = 4-phase shadow)
                asm volatile("s_waitcnt vmcnt(8)" ::: "memory");
            } else {
                // retire sb-kh0 pair (issued kt ph0 = 3-phase shadow)
                asm volatile("s_waitcnt vmcnt(4)" ::: "memory");
            }
            __builtin_amdgcn_s_barrier();
            asm volatile("s_waitcnt lgkmcnt(0)" ::: "memory");
            __builtin_amdgcn_s_setprio(1);
#pragma unroll
            for (int mt = 0; mt < 4; ++mt)
#pragma unroll
                for (int nt = 0; nt < 4; ++nt)
                    acc[mt + 4][nt] = __builtin_amdgcn_mfma_f32_16x16x32_f16(af[mt], bf[nt],
                                                                             acc[mt + 4][nt], 0, 0, 0);
            __builtin_amdgcn_s_setprio(0);
        }
    }

    // ---- Peeled tail kt=63 (buf1): no staging ----
    {
        const int rb = 32768;
#pragma unroll
        for (int kh = 0; kh < 2; ++kh) {
            const int rA = rb + kh * 16384;
            const int rB = rA + 8192;
            half8 af[4], bf[4];
#pragma unroll
            for (int nt = 0; nt < 4; ++nt) bf[nt] = *(const half8*)&lds[rB + nt * 512 + rdB];
#pragma unroll
            for (int mt = 0; mt < 4; ++mt) af[mt] = *(const half8*)&lds[rA + mt * 512 + rdA];
            __builtin_amdgcn_s_barrier();
            asm volatile("s_waitcnt lgkmcnt(0)" ::: "memory");
            __builtin_amdgcn_s_setprio(1);
#pragma unroll
            for (int mt = 0; mt < 4; ++mt)
#pragma unroll
                for (int nt = 0; nt < 4; ++nt)
                    acc[mt][nt] = __builtin_amdgcn_mfma_f32_16x16x32_f16(af[mt], bf[nt],
                                                                         acc[mt][nt], 0, 0, 0);
            __builtin_amdgcn_s_setprio(0);
#pragma unroll
            for (int mt = 0; mt < 4; ++mt) af[mt] = *(const half8*)&lds[rA + (mt + 4) * 512 + rdA];
            // kh==0: drain buf1-kh1 (last 4 in flight) before ph2 reads it.
            if (kh == 0) asm volatile("s_waitcnt vmcnt(0)" ::: "memory");
            __builtin_amdgcn_s_barrier();
            asm volatile("s_waitcnt lgkmcnt(0)" ::: "memory");
            __builtin_amdgcn_s_setprio(1);
#pragma unroll
            for (int mt = 0; mt < 4; ++mt)
#pragma unroll
                for (int nt = 0; nt < 4; ++nt)
                    acc[mt + 4][nt] = __builtin_amdgcn_mfma_f32_16x16x32_f16(af[mt], bf[nt],
                                                                             acc[mt + 4][nt], 0, 0, 0);
            __builtin_amdgcn_s_setprio(0);
        }
    }

    // Epilogue: C/D layout col=lane&15, row=(lane>>4)*4+reg (verified mapping)
#pragma unroll
    for (int mt = 0; mt < 8; ++mt) {
#pragma unroll
        for (int nt = 0; nt < 4; ++nt) {
#pragma unroll
            for (int r = 0; r < 4; ++r) {
                const int row = rowBase + wr * 128 + mt * 16 + quad * 4 + r;
                const int col = colBase + wc * 64 + nt * 16 + fr;
                C[(size_t)row * N + col] = acc[mt][nt][r];
            }
        }
    }
#undef STAGE
}

// ---------------------------------------------------------------------------
// Row softmax (scale already folded into q): P[i][:] = softmax(S[i][:]) fp16
// ---------------------------------------------------------------------------
__global__ __launch_bounds__(256) void softmax_rows(const float* __restrict__ S,
                                                    _Float16* __restrict__ P) {
    const int row = blockIdx.x;
    const int t   = threadIdx.x;
    const float4* Sr = (const float4*)(S + (size_t)row * N);

    float4 v[4];
    float lmax = -3.0e38f;
#pragma unroll
    for (int r = 0; r < 4; ++r) {
        v[r] = Sr[t + 256 * r];
        lmax = fmaxf(lmax, fmaxf(fmaxf(v[r].x, v[r].y), fmaxf(v[r].z, v[r].w)));
    }
#pragma unroll
    for (int off = 32; off; off >>= 1) lmax = fmaxf(lmax, __shfl_xor(lmax, off, 64));
    __shared__ float redm[4], reds[4];
    const int wave = t >> 6, lane = t & 63;
    if (lane == 0) redm[wave] = lmax;
    __syncthreads();
    const float m = fmaxf(fmaxf(redm[0], redm[1]), fmaxf(redm[2], redm[3]));

    float lsum = 0.f;
#pragma unroll
    for (int r = 0; r < 4; ++r) {
        v[r].x = __expf(v[r].x - m);
        v[r].y = __expf(v[r].y - m);
        v[r].z = __expf(v[r].z - m);
        v[r].w = __expf(v[r].w - m);
        lsum += (v[r].x + v[r].y) + (v[r].z + v[r].w);
    }
#pragma unroll
    for (int off = 32; off; off >>= 1) lsum += __shfl_xor(lsum, off, 64);
    if (lane == 0) reds[wave] = lsum;
    __syncthreads();
    const float inv = 1.0f / (((reds[0] + reds[1]) + (reds[2] + reds[3])));

#pragma unroll
    for (int r = 0; r < 4; ++r) {
        half4v o = {(_Float16)(v[r].x * inv), (_Float16)(v[r].y * inv),
                    (_Float16)(v[r].z * inv), (_Float16)(v[r].w * inv)};
        *(half4v*)(P + (size_t)row * N + (t + 256 * r) * 4) = o;
    }
}

// ---------------------------------------------------------------------------
extern "C" void kernel_launch(void* const* d_in, const int* in_sizes, int n_in,
                              void* d_out, int out_size, void* d_ws, size_t ws_size,
                              hipStream_t stream) {
    const float* x = (const float*)d_in[0];
    float* out     = (float*)d_out;
    char* ws       = (char*)d_ws;

    _Float16* qh = (_Float16*)(ws);                    // 32 MB
    _Float16* kh = (_Float16*)(ws + (32ull << 20));    // 32 MB
    _Float16* vt = (_Float16*)(ws + (64ull << 20));    // 32 MB
    float*    S  = (float*)   (ws + (96ull << 20));    // 64 MB
    _Float16* P  = qh;  // qh is dead after GEMM1; alias P over it

    pack_qk     <<<8192, 256, 0, stream>>>(x, qh, kh);
    transpose_v <<<dim3(64, 64), 256, 0, stream>>>(x, vt);
    gemm_nt256  <<<dim3(16, 16), 512, 0, stream>>>(qh, kh, S);
    softmax_rows<<<4096, 256, 0, stream>>>(S, P);
    gemm_nt256  <<<dim3(16, 16), 512, 0, stream>>>(P, vt, out);
}

// Round 6
// 524.698 us; speedup vs baseline: 1.0718x; 1.0718x over previous
//
#include <hip/hip_runtime.h>
#include <hip/hip_bf16.h>
#include <cstdint>

// Problem constants: x is (4096, 3, 4096) fp32; q/k/v are (4096, 4096).
#define N 4096
#define ROWSTRIDE 12288  // 3*4096 floats per n-index

typedef __attribute__((ext_vector_type(8))) _Float16 half8;
typedef __attribute__((ext_vector_type(4))) _Float16 half4v;
typedef __attribute__((ext_vector_type(4))) float floatx4;

// ---------------------------------------------------------------------------
// Pack q,k (fp32 strided rows) -> fp16 dense row-major. q is pre-scaled by 0.5
// 32B loads / 16B stores per thread.
// ---------------------------------------------------------------------------
__global__ __launch_bounds__(256) void pack_qk(const float* __restrict__ x,
                                               _Float16* __restrict__ qh,
                                               _Float16* __restrict__ kh) {
    const size_t tid = (size_t)blockIdx.x * 256 + threadIdx.x;  // 4096*512 threads
    const int i  = (int)(tid >> 9);   // row 0..4095
    const int c8 = (int)(tid & 511);  // 8-float chunk within 4096-wide row
    const float4* xr = (const float4*)(x + (size_t)i * ROWSTRIDE);
    float4 qa = xr[c8 * 2], qb = xr[c8 * 2 + 1];
    float4 ka = xr[1024 + c8 * 2], kb = xr[1024 + c8 * 2 + 1];
    half8 qo = {(_Float16)(qa.x * 0.5f), (_Float16)(qa.y * 0.5f),
                (_Float16)(qa.z * 0.5f), (_Float16)(qa.w * 0.5f),
                (_Float16)(qb.x * 0.5f), (_Float16)(qb.y * 0.5f),
                (_Float16)(qb.z * 0.5f), (_Float16)(qb.w * 0.5f)};
    half8 ko = {(_Float16)ka.x, (_Float16)ka.y, (_Float16)ka.z, (_Float16)ka.w,
                (_Float16)kb.x, (_Float16)kb.y, (_Float16)kb.z, (_Float16)kb.w};
    *(half8*)(qh + (size_t)i * N + c8 * 8) = qo;
    *(half8*)(kh + (size_t)i * N + c8 * 8) = ko;
}

// ---------------------------------------------------------------------------
// v (fp32, strided rows) -> vt fp16 with vt[d][j] = v[j][d]
// 64(j) x 64(d) tile; stores are 8 lanes x 16B = 128B contiguous segments.
// ---------------------------------------------------------------------------
__global__ __launch_bounds__(256) void transpose_v(const float* __restrict__ x,
                                                   _Float16* __restrict__ vt) {
    __shared__ float tile[64][65];  // +1 pad: store-phase reads ~2-way (free)
    const int j0 = blockIdx.x * 64;  // v row block
    const int d0 = blockIdx.y * 64;  // v col block
    const int t  = threadIdx.x;
#pragma unroll
    for (int it = 0; it < 4; ++it) {
        const int r  = it * 16 + (t >> 4);  // 0..63
        const int c4 = t & 15;              // float4 within 64 cols
        const float4 val =
            *(const float4*)(x + (size_t)(j0 + r) * ROWSTRIDE + 8192 + d0 + c4 * 4);
        tile[r][c4 * 4 + 0] = val.x;
        tile[r][c4 * 4 + 1] = val.y;
        tile[r][c4 * 4 + 2] = val.z;
        tile[r][c4 * 4 + 3] = val.w;
    }
    __syncthreads();
#pragma unroll
    for (int it = 0; it < 2; ++it) {
        const int dr = it * 32 + (t >> 3);  // 0..63: d row
        const int jc = t & 7;               // 8-wide j chunk
        half8 o;
#pragma unroll
        for (int jj = 0; jj < 8; ++jj) o[jj] = (_Float16)tile[jc * 8 + jj][dr];
        *(half8*)(vt + (size_t)(d0 + dr) * N + j0 + jc * 8) = o;
    }
}

// ---------------------------------------------------------------------------
// NT GEMM, fp16 in / fp32 out, M=N=K=4096: C[i][j] = sum_k A[i][k]*Bt[j][k]
//
// REVERTED to the round-1 schedule (measured 120.7 us, MfmaUtil 53%, 0 bank
// conflicts). Post-mortem of the deep-prefetch variant (151 us): the LDS pipe
// is co-critical (~2816 cyc/K-tile vs ~2483 MFMA); concentrating the 8 stage
// loads into phases 0-1 piled LDS writes onto read-heavy phases and serialized
// the critical pipe. Balanced 2-loads-per-phase is the right distribution.
//
// 256x256-tile, single-barrier-per-phase schedule (T1+T2+T3+T4+T5):
//  - 512 threads = 8 waves (2M x 4N); per-wave C = 128x64 (8x4 frags).
//  - LDS 128 KiB = 8 regions [buf][khalf][A|B] of 256 rows x 32 k fp16.
//  - 4 phases per K-tile; each phase: {ds_read frags; stage 1 half-region of
//    kt+1; [vmcnt(4) on phases 1,3] -> s_barrier -> lgkmcnt(0) -> setprio(1)
//    16xMFMA setprio(0)} with NO trailing barrier.
//  - Race-freedom: every staged region's consumer reads sit after a barrier
//    that follows all waves' vmcnt retire of that region; region overwrite is
//    >=3 barriers after last drained read.
//  - T2 swizzle: 16B-chunk c' = c ^ ((row>>1)&3) on ds_read addr, inverse
//    pre-applied on global source addr; LDS dest linear (rule #21).
//  - T1: XCD-bijective block swizzle (256 blocks = 8 XCDs x 32).
// ---------------------------------------------------------------------------
#define GL2LDS(g, l)                                                                     \
    __builtin_amdgcn_global_load_lds((const __attribute__((address_space(1))) void*)(g), \
                                     (__attribute__((address_space(3))) void*)(l), 16, 0, 0)

__global__ __launch_bounds__(512, 2) void gemm_nt256(const _Float16* __restrict__ A,
                                                     const _Float16* __restrict__ Bt,
                                                     float* __restrict__ C) {
    __shared__ _Float16 lds[65536];  // 128 KiB
    const int t    = threadIdx.x;
    const int wave = t >> 6;
    const int lane = t & 63;
    const int wr   = wave >> 2;  // 0..1: M half
    const int wc   = wave & 3;   // 0..3: N quarter

    // XCD-aware bijective swizzle: 256 workgroups, 8 XCDs, 32 contiguous each.
    const int orig = blockIdx.y * 16 + blockIdx.x;
    const int wg   = (orig & 7) * 32 + (orig >> 3);
    const int rowBase = (wg >> 4) * 256;
    const int colBase = (wg & 15) * 256;

    floatx4 acc[8][4] = {};

    // ---- staging addressing (pre-swizzled global source; linear LDS dest) ----
    const int sRow = t >> 2;
    const int sCg  = (t & 3) ^ ((t >> 3) & 3);  // chunk ^ (row>>1)&3
    const _Float16* gA = A  + (size_t)(rowBase + sRow) * N + sCg * 8;
    const _Float16* gB = Bt + (size_t)(colBase + sRow) * N + sCg * 8;
    const int ldsW = wave * 512;  // wave-uniform base within half-region (halves)

    // ---- fragment read addressing (swizzled chunk) ----
    const int fr   = lane & 15;
    const int quad = lane >> 4;
    const int swc  = quad ^ ((fr >> 1) & 3);
    const int rdA  = (wr * 128 + fr) * 32 + swc * 8;  // + mt*512 + region
    const int rdB  = (wc * 64 + fr) * 32 + swc * 8;   // + nt*512 + region

    // Region offsets (halves): [buf]*32768 + [khalf]*16384 + [B]*8192
#define STAGE(regOff, g, kOff)                                                  \
    do {                                                                        \
        GL2LDS((g) + (kOff), &lds[(regOff) + ldsW]);                            \
        GL2LDS((g) + (kOff) + (size_t)128 * N, &lds[(regOff) + 4096 + ldsW]);   \
    } while (0)

    // Prologue: stage kt=0 into buf0 (A-kh0, B-kh0, A-kh1, B-kh1).
    STAGE(0, gA, 0);
    STAGE(8192, gB, 0);
    STAGE(16384, gA, 32);
    STAGE(24576, gB, 32);
    asm volatile("s_waitcnt vmcnt(4)" ::: "memory");  // kh0 landed; kh1 in flight
    __builtin_amdgcn_s_barrier();

    for (int kt = 0; kt < 63; ++kt) {
        const int rb = (kt & 1) * 32768;  // read buffer
        const int sb = rb ^ 32768;        // stage buffer (kt+1)
        const int kNext = (kt + 1) * 64;
#pragma unroll
        for (int kh = 0; kh < 2; ++kh) {
            const int rA = rb + kh * 16384;
            const int rB = rA + 8192;
            half8 af[4], bf[4];
            // ---- phase lo: 8 frag reads + A half-region stage ----
#pragma unroll
            for (int nt = 0; nt < 4; ++nt) bf[nt] = *(const half8*)&lds[rB + nt * 512 + rdB];
#pragma unroll
            for (int mt = 0; mt < 4; ++mt) af[mt] = *(const half8*)&lds[rA + mt * 512 + rdA];
            STAGE(sb + kh * 16384, gA, kNext + kh * 32);
            __builtin_amdgcn_s_barrier();
            asm volatile("s_waitcnt lgkmcnt(0)" ::: "memory");
            __builtin_amdgcn_s_setprio(1);
#pragma unroll
            for (int mt = 0; mt < 4; ++mt)
#pragma unroll
                for (int nt = 0; nt < 4; ++nt)
                    acc[mt][nt] = __builtin_amdgcn_mfma_f32_16x16x32_f16(af[mt], bf[nt],
                                                                         acc[mt][nt], 0, 0, 0);
            __builtin_amdgcn_s_setprio(0);
            // ---- phase hi: 4 frag reads (A rows 64-127) + B half-region stage ----
#pragma unroll
            for (int mt = 0; mt < 4; ++mt) af[mt] = *(const half8*)&lds[rA + (mt + 4) * 512 + rdA];
            STAGE(sb + kh * 16384 + 8192, gB, kNext + kh * 32);
            // Counted guard: 8 outstanding; retire oldest 4 (the half-regions the
            // next phase-pair reads), keep 4 in flight. Never vmcnt(0).
            asm volatile("s_waitcnt vmcnt(4)" ::: "memory");
            __builtin_amdgcn_s_barrier();
            asm volatile("s_waitcnt lgkmcnt(0)" ::: "memory");
            __builtin_amdgcn_s_setprio(1);
#pragma unroll
            for (int mt = 0; mt < 4; ++mt)
#pragma unroll
                for (int nt = 0; nt < 4; ++nt)
                    acc[mt + 4][nt] = __builtin_amdgcn_mfma_f32_16x16x32_f16(af[mt], bf[nt],
                                                                             acc[mt + 4][nt], 0, 0, 0);
            __builtin_amdgcn_s_setprio(0);
        }
    }

    // ---- Peeled tail kt=63 (buf1): no staging; drain with vmcnt(0) ----
    {
        const int rb = 32768;
#pragma unroll
        for (int kh = 0; kh < 2; ++kh) {
            const int rA = rb + kh * 16384;
            const int rB = rA + 8192;
            half8 af[4], bf[4];
#pragma unroll
            for (int nt = 0; nt < 4; ++nt) bf[nt] = *(const half8*)&lds[rB + nt * 512 + rdB];
#pragma unroll
            for (int mt = 0; mt < 4; ++mt) af[mt] = *(const half8*)&lds[rA + mt * 512 + rdA];
            __builtin_amdgcn_s_barrier();
            asm volatile("s_waitcnt lgkmcnt(0)" ::: "memory");
            __builtin_amdgcn_s_setprio(1);
#pragma unroll
            for (int mt = 0; mt < 4; ++mt)
#pragma unroll
                for (int nt = 0; nt < 4; ++nt)
                    acc[mt][nt] = __builtin_amdgcn_mfma_f32_16x16x32_f16(af[mt], bf[nt],
                                                                         acc[mt][nt], 0, 0, 0);
            __builtin_amdgcn_s_setprio(0);
#pragma unroll
            for (int mt = 0; mt < 4; ++mt) af[mt] = *(const half8*)&lds[rA + (mt + 4) * 512 + rdA];
            // kh==0: ensure kh1 half-regions (last 4 in flight) have landed before
            // any wave reads them after the next barrier.
            if (kh == 0) asm volatile("s_waitcnt vmcnt(0)" ::: "memory");
            __builtin_amdgcn_s_barrier();
            asm volatile("s_waitcnt lgkmcnt(0)" ::: "memory");
            __builtin_amdgcn_s_setprio(1);
#pragma unroll
            for (int mt = 0; mt < 4; ++mt)
#pragma unroll
                for (int nt = 0; nt < 4; ++nt)
                    acc[mt + 4][nt] = __builtin_amdgcn_mfma_f32_16x16x32_f16(af[mt], bf[nt],
                                                                             acc[mt + 4][nt], 0, 0, 0);
            __builtin_amdgcn_s_setprio(0);
        }
    }

    // Epilogue: C/D layout col=lane&15, row=(lane>>4)*4+reg (verified mapping)
#pragma unroll
    for (int mt = 0; mt < 8; ++mt) {
#pragma unroll
        for (int nt = 0; nt < 4; ++nt) {
#pragma unroll
            for (int r = 0; r < 4; ++r) {
                const int row = rowBase + wr * 128 + mt * 16 + quad * 4 + r;
                const int col = colBase + wc * 64 + nt * 16 + fr;
                C[(size_t)row * N + col] = acc[mt][nt][r];
            }
        }
    }
#undef STAGE
}

// ---------------------------------------------------------------------------
// Row softmax (scale already folded into q): P[i][:] = softmax(S[i][:]) fp16
// One row per WAVE (no __syncthreads, shuffle-only reductions); 4 rows/block.
// Per lane: 8 x 32B reads, 8 x 16B stores, all coalesced.
// ---------------------------------------------------------------------------
__global__ __launch_bounds__(256) void softmax_rows(const float* __restrict__ S,
                                                    _Float16* __restrict__ P) {
    const int wave = threadIdx.x >> 6;
    const int lane = threadIdx.x & 63;
    const int row  = blockIdx.x * 4 + wave;
    const float4* Sr = (const float4*)(S + (size_t)row * N);

    float4 v[16];
    float lmax = -3.0e38f;
#pragma unroll
    for (int r = 0; r < 8; ++r) {
        const int c8 = lane + 64 * r;  // 8-float chunk index
        v[2 * r]     = Sr[2 * c8];
        v[2 * r + 1] = Sr[2 * c8 + 1];
        lmax = fmaxf(lmax, fmaxf(fmaxf(v[2 * r].x, v[2 * r].y),
                                 fmaxf(v[2 * r].z, v[2 * r].w)));
        lmax = fmaxf(lmax, fmaxf(fmaxf(v[2 * r + 1].x, v[2 * r + 1].y),
                                 fmaxf(v[2 * r + 1].z, v[2 * r + 1].w)));
    }
#pragma unroll
    for (int off = 32; off; off >>= 1) lmax = fmaxf(lmax, __shfl_xor(lmax, off, 64));

    float lsum = 0.f;
#pragma unroll
    for (int r = 0; r < 16; ++r) {
        v[r].x = __expf(v[r].x - lmax);
        v[r].y = __expf(v[r].y - lmax);
        v[r].z = __expf(v[r].z - lmax);
        v[r].w = __expf(v[r].w - lmax);
        lsum += (v[r].x + v[r].y) + (v[r].z + v[r].w);
    }
#pragma unroll
    for (int off = 32; off; off >>= 1) lsum += __shfl_xor(lsum, off, 64);
    const float inv = 1.0f / lsum;

#pragma unroll
    for (int r = 0; r < 8; ++r) {
        const int c8 = lane + 64 * r;
        half8 o = {(_Float16)(v[2 * r].x * inv),     (_Float16)(v[2 * r].y * inv),
                   (_Float16)(v[2 * r].z * inv),     (_Float16)(v[2 * r].w * inv),
                   (_Float16)(v[2 * r + 1].x * inv), (_Float16)(v[2 * r + 1].y * inv),
                   (_Float16)(v[2 * r + 1].z * inv), (_Float16)(v[2 * r + 1].w * inv)};
        *(half8*)(P + (size_t)row * N + c8 * 8) = o;
    }
}

// ---------------------------------------------------------------------------
extern "C" void kernel_launch(void* const* d_in, const int* in_sizes, int n_in,
                              void* d_out, int out_size, void* d_ws, size_t ws_size,
                              hipStream_t stream) {
    const float* x = (const float*)d_in[0];
    float* out     = (float*)d_out;
    char* ws       = (char*)d_ws;

    _Float16* qh = (_Float16*)(ws);                    // 32 MB
    _Float16* kh = (_Float16*)(ws + (32ull << 20));    // 32 MB
    _Float16* vt = (_Float16*)(ws + (64ull << 20));    // 32 MB
    float*    S  = (float*)   (ws + (96ull << 20));    // 64 MB
    _Float16* P  = qh;  // qh is dead after GEMM1; alias P over it

    pack_qk     <<<8192, 256, 0, stream>>>(x, qh, kh);
    transpose_v <<<dim3(64, 64), 256, 0, stream>>>(x, vt);
    gemm_nt256  <<<dim3(16, 16), 512, 0, stream>>>(qh, kh, S);
    softmax_rows<<<1024, 256, 0, stream>>>(S, P);
    gemm_nt256  <<<dim3(16, 16), 512, 0, stream>>>(P, vt, out);
}